// Round 15
// baseline (119.376 us; speedup 1.0000x reference)
//
#include <hip/hip_runtime.h>
#include <cstdint>
#include <cstddef>

#define NEGV (-1e30f)
#define IL2f 1.44269504088896340736f
#define LN2f 0.693147180559945309417f

__device__ __forceinline__ float exp2_hw(float x) { return __builtin_amdgcn_exp2f(x); }
__device__ __forceinline__ float log2_hw(float x) { return __builtin_amdgcn_logf(x); }

constexpr int Nn = 64, Cc = 64, Tt = 4000, Ss = 100;

__device__ __forceinline__ float wave_shr1(float x) {  // lane n <- lane n-1
    return __int_as_float(__builtin_amdgcn_update_dpp(0, __float_as_int(x), 0x138, 0xF, 0xF, true));
}
__device__ __forceinline__ float wave_shl1(float x) {  // lane n <- lane n+1
    return __int_as_float(__builtin_amdgcn_update_dpp(0, __float_as_int(x), 0x130, 0xF, 0xF, true));
}
__device__ __forceinline__ int wave_shr1_i(int x) {
    return __builtin_amdgcn_update_dpp(0, x, 0x138, 0xF, 0xF, true);
}
__device__ __forceinline__ int wave_shl1_i(int x) {
    return __builtin_amdgcn_update_dpp(0, x, 0x130, 0xF, 0xF, true);
}

typedef float f4 __attribute__((ext_vector_type(4)));
#define LD4(p) (*(const f4*)(p))

__device__ __forceinline__ void gload16(const float* g, float* l) {
    __builtin_amdgcn_global_load_lds(
        (const __attribute__((address_space(1))) void*)g,
        (__attribute__((address_space(3))) void*)l, 16, 0, 0);
}

// ------- Kernel 1a: PARTIAL denominator, 4-way class split (16 classes each) -------
__global__ __launch_bounds__(256) void ctc_denom_part4(
    const float* __restrict__ logits, float* __restrict__ dP)
{
    const int t4 = (blockIdx.x * 256 + threadIdx.x) * 4;
    const int n = blockIdx.y;
    const int c0 = blockIdx.z * 16;
    if (t4 >= Tt) return;
    const float* __restrict__ p = logits + ((size_t)(n * Cc + c0)) * Tt + t4;
    f4 m, s;
    {
        f4 v = LD4(p);
        #pragma unroll
        for (int i = 0; i < 4; ++i) { m[i] = v[i] * IL2f; s[i] = 1.f; }
    }
    #pragma unroll 4
    for (int c = 1; c < 16; ++c) {
        f4 v = LD4(p + (size_t)c * Tt);
        #pragma unroll
        for (int i = 0; i < 4; ++i) {
            float vi = v[i] * IL2f;
            float nm = fmaxf(m[i], vi);
            s[i] = s[i] * exp2_hw(m[i] - nm) + exp2_hw(vi - nm);
            m[i] = nm;
        }
    }
    f4 o;
    #pragma unroll
    for (int i = 0; i < 4; ++i) o[i] = m[i] + log2_hw(s[i]);
    *(f4*)(dP + ((size_t)blockIdx.z * Nn + n) * Tt + t4) = o;
}

// ------- Kernel 1a' (tier2): full denominator in one pass -------
__global__ __launch_bounds__(256) void ctc_denom_kernel(
    const float* __restrict__ logits, float* __restrict__ d2)
{
    const int t4 = (blockIdx.x * 256 + threadIdx.x) * 4;
    const int n = blockIdx.y;
    if (t4 >= Tt) return;
    const float* __restrict__ p = logits + (size_t)n * Cc * Tt + t4;
    f4 m, s;
    {
        f4 v = LD4(p);
        #pragma unroll
        for (int i = 0; i < 4; ++i) { m[i] = v[i] * IL2f; s[i] = 1.f; }
    }
    #pragma unroll 4
    for (int c = 1; c < Cc; ++c) {
        f4 v = LD4(p + (size_t)c * Tt);
        #pragma unroll
        for (int i = 0; i < 4; ++i) {
            float vi = v[i] * IL2f;
            float nm = fmaxf(m[i], vi);
            s[i] = s[i] * exp2_hw(m[i] - nm) + exp2_hw(vi - nm);
            m[i] = nm;
        }
    }
    f4 o;
    #pragma unroll
    for (int i = 0; i < 4; ++i) o[i] = m[i] + log2_hw(s[i]);
    *(f4*)(d2 + (size_t)n * Tt + t4) = o;
}

// ------- merge 4 partials into dP[0] (tier3 path) -------
__global__ __launch_bounds__(256) void ctc_denom_merge4(float* __restrict__ dP)
{
    const int t4 = (blockIdx.x * 256 + threadIdx.x) * 4;
    const int n = blockIdx.y;
    if (t4 >= Tt) return;
    f4 a = LD4(dP + (size_t)n * Tt + t4);
    f4 b = LD4(dP + ((size_t)Nn + n) * Tt + t4);
    f4 c = LD4(dP + ((size_t)2 * Nn + n) * Tt + t4);
    f4 e = LD4(dP + ((size_t)3 * Nn + n) * Tt + t4);
    f4 d;
    #pragma unroll
    for (int i = 0; i < 4; ++i) {
        const float mm = fmaxf(fmaxf(a[i], b[i]), fmaxf(c[i], e[i]));
        d[i] = mm + log2_hw(exp2_hw(a[i] - mm) + exp2_hw(b[i] - mm) +
                            exp2_hw(c[i] - mm) + exp2_hw(e[i] - mm));
    }
    *(f4*)(dP + (size_t)n * Tt + t4) = d;
}

// ------- Kernel 1b: membership-filtered probabilities (+ optional 4-way merge) -------
template<bool MERGE4>
__global__ __launch_bounds__(256) void ctc_prob_sel(
    const float* __restrict__ logits, const float* __restrict__ dP,
    const int* __restrict__ targets, const int* __restrict__ tlen,
    float* __restrict__ P)
{
    const int n = blockIdx.y;
    const int c0 = blockIdx.z * 8;
    __shared__ int needs;
    if (threadIdx.x == 0) needs = (c0 == 0) ? 1 : 0;   // blank always needed
    __syncthreads();
    const int tl = tlen[n];
    if ((int)threadIdx.x < min(tl, Ss)) {
        const int rel = targets[n * Ss + threadIdx.x] - c0;
        if (rel >= 0 && rel < 8) atomicOr(&needs, 1 << rel);
    }
    __syncthreads();
    const int nd = needs;
    if (nd == 0) return;
    const int t4 = (blockIdx.x * 256 + threadIdx.x) * 4;
    if (t4 >= Tt) return;
    f4 d;
    if constexpr (MERGE4) {
        f4 a = LD4(dP + (size_t)n * Tt + t4);
        f4 b = LD4(dP + ((size_t)Nn + n) * Tt + t4);
        f4 c = LD4(dP + ((size_t)2 * Nn + n) * Tt + t4);
        f4 e = LD4(dP + ((size_t)3 * Nn + n) * Tt + t4);
        #pragma unroll
        for (int i = 0; i < 4; ++i) {
            const float mm = fmaxf(fmaxf(a[i], b[i]), fmaxf(c[i], e[i]));
            d[i] = mm + log2_hw(exp2_hw(a[i] - mm) + exp2_hw(b[i] - mm) +
                                exp2_hw(c[i] - mm) + exp2_hw(e[i] - mm));
        }
    } else {
        d = LD4(dP + (size_t)n * Tt + t4);
    }
    const float* __restrict__ src = logits + ((size_t)(n * Cc + c0)) * Tt + t4;
    float* __restrict__ dst = P + ((size_t)(n * Cc + c0)) * Tt + t4;
    #pragma unroll
    for (int c = 0; c < 8; ++c) {
        if ((nd >> c) & 1) {
            f4 v = LD4(src + (size_t)c * Tt);
            f4 o;
            #pragma unroll
            for (int i = 0; i < 4; ++i) o[i] = exp2_hw(fmaf(v[i], IL2f, -d[i]));
            *(f4*)(dst + (size_t)c * Tt) = o;
        }
    }
}

// ---------------- Kernel 2: fwd/bwd recurrence ----------------
// R12 staging structure (32-step groups, 2-slot LDS ring, counted vmcnt).
// R15: full-group bodies are BRANCH-FREE SCALAR with the four per-step
// recurrences written as interleaved independent chains (1 DPP + 3 add +
// 3 fma + 4 mul = 11 VALU/step) — tests whether fb is ILP-starved (packed
// f2 body fused them into 2 chains + shuffle movs) vs serialization-bound.
template<bool PRE>
__global__ __launch_bounds__(64) void ctc_fb_kernel(
    const float* __restrict__ PR, const int* __restrict__ targets,
    const int* __restrict__ tlen, const int* __restrict__ ilen,
    const float* __restrict__ d2, float* __restrict__ wsA, float* __restrict__ wsB)
{
    constexpr int NA = PRE ? 3 : 4;
    constexpr int NLD = NA * 8;
    __shared__ float lds[2][NA][8][64][4];

    const int bid = blockIdx.x;
    const int n = bid >> 1;
    const bool bwd = bid & 1;
    const int lane = threadIdx.x;
    const int tl = tlen[n];
    const int Tn = ilen[n];
    const int L = 2 * tl + 1;
    const int mid = Tn >> 1;
    const int s0 = 4 * lane;

    const int j1 = min(2 * lane, Ss - 1);
    const int j3 = min(2 * lane + 1, Ss - 1);
    const int base = n * Ss;
    const int tg1 = targets[base + j1];
    const int tg3 = targets[base + j3];
    const int tg1m = targets[base + max(2 * lane - 1, 0)];
    const int tg3p = targets[base + min(2 * lane + 2, Ss - 1)];

    const float sk1f = ((s0 + 1 >= 3) && (tg1 != tg1m)) ? 1.f : 0.f;
    const float sk3f = (tg3 != tg1) ? 1.f : 0.f;
    const float sk1b = ((s0 + 3 < L) && (tg3 != tg1)) ? 1.f : 0.f;
    const float sk3b = ((s0 + 5 < L) && (tg3p != tg3)) ? 1.f : 0.f;

    const float* __restrict__ rB = PR + (size_t)(n * Cc) * Tt;
    const float* __restrict__ r1 = PR + (size_t)(n * Cc + tg1) * Tt;
    const float* __restrict__ r3 = PR + (size_t)(n * Cc + tg3) * Tt;
    const float* __restrict__ rD = d2 + (size_t)n * Tt;

    float a0, a1, a2, a3;
    int E = 0;

    if (!bwd) {
        float pB0, p10;
        if constexpr (PRE) { pB0 = rB[0]; p10 = r1[0]; }
        else {
            const float dv = rD[0];
            pB0 = exp2_hw(fmaf(rB[0], IL2f, -dv));
            p10 = exp2_hw(fmaf(r1[0], IL2f, -dv));
        }
        a0 = (lane == 0) ? pB0 : 0.f;
        a1 = (lane == 0) ? p10 : 0.f;
        a2 = 0.f; a3 = 0.f;
    } else {
        const int te = Tn - 1;
        float pBe, p1e, p3e;
        if constexpr (PRE) { pBe = rB[te]; p1e = r1[te]; p3e = r3[te]; }
        else {
            const float dv = rD[te];
            pBe = exp2_hw(fmaf(rB[te], IL2f, -dv));
            p1e = exp2_hw(fmaf(r1[te], IL2f, -dv));
            p3e = exp2_hw(fmaf(r3[te], IL2f, -dv));
        }
        const int sl = 2 * tl;
        a0 = (s0 == sl) ? pBe : 0.f;
        a1 = (s0 + 1 == sl - 1) ? p1e : 0.f;
        a2 = (s0 + 2 == sl) ? pBe : 0.f;
        a3 = (s0 + 3 == sl - 1) ? p3e : 0.f;
    }

    #define ISSUE(gg, sl) {                                                         \
        const int bo_ = (gg) * 32;                                                  \
        _Pragma("unroll")                                                           \
        for (int j = 0; j < 8; ++j) {                                               \
            gload16(rB + bo_ + 4 * j, &lds[sl][0][j][0][0]);                        \
            gload16(r1 + bo_ + 4 * j, &lds[sl][1][j][0][0]);                        \
            gload16(r3 + bo_ + 4 * j, &lds[sl][2][j][0][0]);                        \
            if constexpr (!PRE) gload16(rD + bo_ + 4 * j, &lds[sl][NA - 1][j][0][0]); \
        }                                                                           \
    }
    #define WAITG() asm volatile("s_waitcnt vmcnt(%0)" :: "n"(NLD) : "memory")
    #define LOADREGS(slc)                                                           \
        f4 vB[8], vU[8], vW[8], vD[8];                                              \
        _Pragma("unroll")                                                           \
        for (int j = 0; j < 8; ++j) {                                               \
            vB[j] = LD4(&lds[slc][0][j][lane][0]);                                  \
            vU[j] = LD4(&lds[slc][1][j][lane][0]);                                  \
            vW[j] = LD4(&lds[slc][2][j][lane][0]);                                  \
            if constexpr (!PRE) vD[j] = LD4(&lds[slc][NA - 1][j][lane][0]);         \
        }                                                                           \
        (void)vD;

    #define RENORM_S(nb) {                                                          \
        const float mx = fmaxf(fmaxf(a0, a1), fmaxf(a2, a3));                       \
        const int me = (int)(__float_as_uint(mx) >> 23);                            \
        const float s2 = __int_as_float((unsigned)(254 - me) << 23);                \
        a0 *= s2; a1 *= s2; a2 *= s2; a3 *= s2;                                     \
        E = (mx > 0.f) ? (E + me - 127) : (nb);                                     \
    }

    // One F step, branch-free, 4 interleaved chains.
    #define FSTEP(pB, p1, p3, sc, sk1fs) {                                          \
        const float u3  = wave_shr1(a3);                                            \
        const float s32 = a3 + a2;                                                  \
        const float s21 = a2 + a1;                                                  \
        const float s10 = a1 + a0;                                                  \
        const float h3  = fmaf(a1, sk3f, s32);                                      \
        const float h0  = fmaf(u3, sc, a0);                                         \
        const float h1  = fmaf(u3, sk1fs, s10);                                     \
        a3 = h3 * (p3); a2 = s21 * (pB); a1 = h1 * (p1); a0 = h0 * (pB);            \
    }
    // One B step, branch-free.
    #define BSTEP(pB, p1, p3, sc, sk3bs) {                                          \
        const float d0  = wave_shl1(a0);                                            \
        const float d1  = wave_shl1(a1);                                            \
        const float s01 = a0 + a1;                                                  \
        const float s12 = a1 + a2;                                                  \
        const float s23 = a2 + a3;                                                  \
        const float h1  = fmaf(a3, sk1b, s12);                                      \
        const float t3  = fmaf(d0, sc, a3);                                         \
        const float h3  = fmaf(d1, sk3bs, t3);                                      \
        a0 = s01 * (pB); a2 = s23 * (pB); a1 = h1 * (p1); a3 = h3 * (p3);           \
    }

    if (!bwd) {
        const int tB = mid;
        const int gHi = tB >> 5;

        #define BODY_F_G(gg) {                                                      \
            _Pragma("unroll")                                                       \
            for (int w = 0; w < 4; ++w) {                                           \
                const int Eu = wave_shr1_i(E);                                      \
                const int eb = min(max(127 + (Eu - E), 0), 230);                    \
                const float sc = __int_as_float((unsigned)eb << 23);                \
                const float sk1fs = sk1f * sc;                                      \
                _Pragma("unroll")                                                   \
                for (int kk = 0; kk < 8; ++kk) {                                    \
                    const int k = w * 8 + kk;                                       \
                    const int t = (gg) * 32 + k;                                    \
                    if (t >= 1 && t <= tB) {                                        \
                        float pB, p1, p3;                                           \
                        if constexpr (PRE) {                                        \
                            pB = vB[k >> 2][k & 3]; p1 = vU[k >> 2][k & 3];         \
                            p3 = vW[k >> 2][k & 3];                                 \
                        } else {                                                    \
                            const float dv = vD[k >> 2][k & 3];                     \
                            pB = exp2_hw(fmaf(vB[k >> 2][k & 3], IL2f, -dv));       \
                            p1 = exp2_hw(fmaf(vU[k >> 2][k & 3], IL2f, -dv));       \
                            p3 = exp2_hw(fmaf(vW[k >> 2][k & 3], IL2f, -dv));       \
                        }                                                           \
                        FSTEP(pB, p1, p3, sc, sk1fs);                               \
                    }                                                               \
                }                                                                   \
                RENORM_S(Eu);                                                       \
            }                                                                       \
        }

        #define BODY_F_F() {                                                        \
            _Pragma("unroll")                                                       \
            for (int w = 0; w < 4; ++w) {                                           \
                const int Eu = wave_shr1_i(E);                                      \
                const int eb = min(max(127 + (Eu - E), 0), 230);                    \
                const float sc = __int_as_float((unsigned)eb << 23);                \
                const float sk1fs = sk1f * sc;                                      \
                _Pragma("unroll")                                                   \
                for (int kk = 0; kk < 8; ++kk) {                                    \
                    const int k = w * 8 + kk;                                       \
                    FSTEP(vB[k >> 2][k & 3], vU[k >> 2][k & 3], vW[k >> 2][k & 3],  \
                          sc, sk1fs);                                               \
                }                                                                   \
                RENORM_S(Eu);                                                       \
            }                                                                       \
        }

        ISSUE(0, 0);
        int cur = 0;
        for (int g = 0; g <= gHi; ++g) {
            ISSUE(min(g + 1, gHi), cur ^ 1);
            WAITG();
            LOADREGS(cur);
            cur ^= 1;
            if (PRE && g >= 1 && g * 32 + 31 <= tB) { BODY_F_F(); }
            else                                    { BODY_F_G(g); }
        }
        #undef BODY_F_G
        #undef BODY_F_F
    } else {
        const int tB = Tn - 2, tA = mid + 1;
        const int gHi = tB >> 5, gLo = tA >> 5;

        #define BODY_B_G(gg) {                                                      \
            _Pragma("unroll")                                                       \
            for (int w = 3; w >= 0; --w) {                                          \
                const int Ed = wave_shl1_i(E);                                      \
                const int eb = min(max(127 + (Ed - E), 0), 230);                    \
                const float sc = __int_as_float((unsigned)eb << 23);                \
                const float sk3bs = sk3b * sc;                                      \
                _Pragma("unroll")                                                   \
                for (int kk = 7; kk >= 0; --kk) {                                   \
                    const int k = w * 8 + kk;                                       \
                    const int t = (gg) * 32 + k;                                    \
                    if (t >= tA && t <= tB) {                                       \
                        float pB, p1, p3;                                           \
                        if constexpr (PRE) {                                        \
                            pB = vB[k >> 2][k & 3]; p1 = vU[k >> 2][k & 3];         \
                            p3 = vW[k >> 2][k & 3];                                 \
                        } else {                                                    \
                            const float dv = vD[k >> 2][k & 3];                     \
                            pB = exp2_hw(fmaf(vB[k >> 2][k & 3], IL2f, -dv));       \
                            p1 = exp2_hw(fmaf(vU[k >> 2][k & 3], IL2f, -dv));       \
                            p3 = exp2_hw(fmaf(vW[k >> 2][k & 3], IL2f, -dv));       \
                        }                                                           \
                        BSTEP(pB, p1, p3, sc, sk3bs);                               \
                    }                                                               \
                }                                                                   \
                RENORM_S(Ed);                                                       \
            }                                                                       \
        }

        #define BODY_B_F() {                                                        \
            _Pragma("unroll")                                                       \
            for (int w = 3; w >= 0; --w) {                                          \
                const int Ed = wave_shl1_i(E);                                      \
                const int eb = min(max(127 + (Ed - E), 0), 230);                    \
                const float sc = __int_as_float((unsigned)eb << 23);                \
                const float sk3bs = sk3b * sc;                                      \
                _Pragma("unroll")                                                   \
                for (int kk = 7; kk >= 0; --kk) {                                   \
                    const int k = w * 8 + kk;                                       \
                    BSTEP(vB[k >> 2][k & 3], vU[k >> 2][k & 3], vW[k >> 2][k & 3],  \
                          sc, sk3bs);                                               \
                }                                                                   \
                RENORM_S(Ed);                                                       \
            }                                                                       \
        }

        ISSUE(gHi, 0);
        int cur = 0;
        for (int g = gHi; g >= gLo; --g) {
            ISSUE(max(g - 1, 0), cur ^ 1);
            WAITG();
            LOADREGS(cur);
            cur ^= 1;
            if (PRE && g * 32 >= tA && g * 32 + 31 <= tB) { BODY_B_F(); }
            else                                          { BODY_B_G(g); }
        }
        #undef BODY_B_G
        #undef BODY_B_F
    }
    #undef ISSUE
    #undef WAITG
    #undef LOADREGS
    #undef RENORM_S
    #undef FSTEP
    #undef BSTEP

    float* dst = (bwd ? wsB : wsA) + n * 256;
    const float Ef = (float)E;
    f4 o;
    o[0] = (s0     < L && a0 > 0.f) ? log2_hw(a0) + Ef : NEGV;
    o[1] = (s0 + 1 < L && a1 > 0.f) ? log2_hw(a1) + Ef : NEGV;
    o[2] = (s0 + 2 < L && a2 > 0.f) ? log2_hw(a2) + Ef : NEGV;
    o[3] = (s0 + 3 < L && a3 > 0.f) ? log2_hw(a3) + Ef : NEGV;
    *(f4*)(dst + s0) = o;
}

// ---------------- Kernel 3: splice alpha*beta, lse over states, mean ----------------
__global__ __launch_bounds__(64) void ctc_combine_kernel(
    const float* __restrict__ wsA, const float* __restrict__ wsB,
    const int* __restrict__ targets, const int* __restrict__ tlen,
    float* __restrict__ out)
{
    const int n = blockIdx.x;
    const int lane = threadIdx.x;
    const int tl = tlen[n];
    const int L = 2 * tl + 1;
    float vals[4];
    float vmax = NEGV;
    #pragma unroll
    for (int k = 0; k < 4; ++k) {
        const int s = lane + (k << 6);
        float v = NEGV;
        if (s < L) {
            const float al = wsA[n * 256 + s];
            const float b0 = wsB[n * 256 + s];
            const float b1 = (s + 1 < L) ? wsB[n * 256 + s + 1] : NEGV;
            const bool skip = (s & 1) && (s + 2 < L) &&
                (targets[n * Ss + (s >> 1) + 1] != targets[n * Ss + (s >> 1)]);
            const float b2 = skip ? wsB[n * 256 + s + 2] : NEGV;
            const float m3 = fmaxf(fmaxf(b0, b1), b2);
            const float B = m3 + log2_hw(exp2_hw(b0 - m3) + exp2_hw(b1 - m3) + exp2_hw(b2 - m3));
            v = al + B;
        }
        vals[k] = v;
        vmax = fmaxf(vmax, v);
    }
    #pragma unroll
    for (int o = 32; o; o >>= 1) vmax = fmaxf(vmax, __shfl_xor(vmax, o));
    float ssum = 0.f;
    #pragma unroll
    for (int k = 0; k < 4; ++k) ssum += exp2_hw(vals[k] - vmax);
    #pragma unroll
    for (int o = 32; o; o >>= 1) ssum += __shfl_xor(ssum, o);
    if (lane == 0) {
        const float total2 = vmax + log2_hw(ssum);
        const float loss = -LN2f * total2;
        atomicAdd(out, loss / ((float)tl * (float)Nn));
    }
}

extern "C" void kernel_launch(void* const* d_in, const int* in_sizes, int n_in,
                              void* d_out, int out_size, void* d_ws, size_t ws_size,
                              hipStream_t stream) {
    const float* logits = (const float*)d_in[0];
    const int* targets  = (const int*)d_in[1];
    const int* tlen     = (const int*)d_in[2];
    const int* ilen     = (const int*)d_in[3];
    float* out = (float*)d_out;

    float* wsA = (float*)d_ws;                         // Nn*256
    float* wsB = wsA + Nn * 256;                       // Nn*256
    float* dP  = wsB + Nn * 256;                       // up to 4 * Nn*Tt partials
    float* P1  = dP + (size_t)4 * Nn * Tt;             // tier1 P
    float* P2  = dP + (size_t)Nn * Tt;                 // tier2 P

    const size_t base = (size_t)Nn * 512;
    const size_t need1 = (base + (size_t)4 * Nn * Tt + (size_t)Nn * Cc * Tt) * 4;
    const size_t need2 = (base + (size_t)Nn * Tt + (size_t)Nn * Cc * Tt) * 4;

    hipMemsetAsync(d_out, 0, sizeof(float), stream);
    if (ws_size >= need1) {
        ctc_denom_part4<<<dim3(4, Nn, 4), 256, 0, stream>>>(logits, dP);
        ctc_prob_sel<true><<<dim3(4, Nn, 8), 256, 0, stream>>>(logits, dP, targets, tlen, P1);
        ctc_fb_kernel<true><<<Nn * 2, 64, 0, stream>>>(P1, targets, tlen, ilen, dP, wsA, wsB);
    } else if (ws_size >= need2) {
        ctc_denom_kernel<<<dim3(4, Nn), 256, 0, stream>>>(logits, dP);
        ctc_prob_sel<false><<<dim3(4, Nn, 8), 256, 0, stream>>>(logits, dP, targets, tlen, P2);
        ctc_fb_kernel<true><<<Nn * 2, 64, 0, stream>>>(P2, targets, tlen, ilen, dP, wsA, wsB);
    } else {
        ctc_denom_part4<<<dim3(4, Nn, 4), 256, 0, stream>>>(logits, dP);
        ctc_denom_merge4<<<dim3(4, Nn), 256, 0, stream>>>(dP);
        ctc_fb_kernel<false><<<Nn * 2, 64, 0, stream>>>(logits, targets, tlen, ilen, dP, wsA, wsB);
    }
    ctc_combine_kernel<<<Nn, 64, 0, stream>>>(wsA, wsB, targets, tlen, out);
}

// Round 16
// 105.975 us; speedup vs baseline: 1.1265x; 1.1265x over previous
//
#include <hip/hip_runtime.h>
#include <cstdint>
#include <cstddef>

#define NEGV (-1e30f)
#define IL2f 1.44269504088896340736f
#define LN2f 0.693147180559945309417f

__device__ __forceinline__ float exp2_hw(float x) { return __builtin_amdgcn_exp2f(x); }
__device__ __forceinline__ float log2_hw(float x) { return __builtin_amdgcn_logf(x); }

constexpr int Nn = 64, Cc = 64, Tt = 4000, Ss = 100;

__device__ __forceinline__ float wave_shr1(float x) {  // lane n <- lane n-1
    return __int_as_float(__builtin_amdgcn_update_dpp(0, __float_as_int(x), 0x138, 0xF, 0xF, true));
}
__device__ __forceinline__ float wave_shl1(float x) {  // lane n <- lane n+1
    return __int_as_float(__builtin_amdgcn_update_dpp(0, __float_as_int(x), 0x130, 0xF, 0xF, true));
}
__device__ __forceinline__ int wave_shr1_i(int x) {
    return __builtin_amdgcn_update_dpp(0, x, 0x138, 0xF, 0xF, true);
}
__device__ __forceinline__ int wave_shl1_i(int x) {
    return __builtin_amdgcn_update_dpp(0, x, 0x130, 0xF, 0xF, true);
}

typedef float f4 __attribute__((ext_vector_type(4)));
typedef float f2 __attribute__((ext_vector_type(2)));
#define LD4(p) (*(const f4*)(p))

__device__ __forceinline__ void gload16(const float* g, float* l) {
    __builtin_amdgcn_global_load_lds(
        (const __attribute__((address_space(1))) void*)g,
        (__attribute__((address_space(3))) void*)l, 16, 0, 0);
}

// ------- Kernel 1a: PARTIAL denominator, 4-way class split (16 classes each) -------
__global__ __launch_bounds__(256) void ctc_denom_part4(
    const float* __restrict__ logits, float* __restrict__ dP)
{
    const int t4 = (blockIdx.x * 256 + threadIdx.x) * 4;
    const int n = blockIdx.y;
    const int c0 = blockIdx.z * 16;
    if (t4 >= Tt) return;
    const float* __restrict__ p = logits + ((size_t)(n * Cc + c0)) * Tt + t4;
    f4 m, s;
    {
        f4 v = LD4(p);
        #pragma unroll
        for (int i = 0; i < 4; ++i) { m[i] = v[i] * IL2f; s[i] = 1.f; }
    }
    #pragma unroll 4
    for (int c = 1; c < 16; ++c) {
        f4 v = LD4(p + (size_t)c * Tt);
        #pragma unroll
        for (int i = 0; i < 4; ++i) {
            float vi = v[i] * IL2f;
            float nm = fmaxf(m[i], vi);
            s[i] = s[i] * exp2_hw(m[i] - nm) + exp2_hw(vi - nm);
            m[i] = nm;
        }
    }
    f4 o;
    #pragma unroll
    for (int i = 0; i < 4; ++i) o[i] = m[i] + log2_hw(s[i]);
    *(f4*)(dP + ((size_t)blockIdx.z * Nn + n) * Tt + t4) = o;
}

// ------- Kernel 1a' (tier2): full denominator in one pass -------
__global__ __launch_bounds__(256) void ctc_denom_kernel(
    const float* __restrict__ logits, float* __restrict__ d2)
{
    const int t4 = (blockIdx.x * 256 + threadIdx.x) * 4;
    const int n = blockIdx.y;
    if (t4 >= Tt) return;
    const float* __restrict__ p = logits + (size_t)n * Cc * Tt + t4;
    f4 m, s;
    {
        f4 v = LD4(p);
        #pragma unroll
        for (int i = 0; i < 4; ++i) { m[i] = v[i] * IL2f; s[i] = 1.f; }
    }
    #pragma unroll 4
    for (int c = 1; c < Cc; ++c) {
        f4 v = LD4(p + (size_t)c * Tt);
        #pragma unroll
        for (int i = 0; i < 4; ++i) {
            float vi = v[i] * IL2f;
            float nm = fmaxf(m[i], vi);
            s[i] = s[i] * exp2_hw(m[i] - nm) + exp2_hw(vi - nm);
            m[i] = nm;
        }
    }
    f4 o;
    #pragma unroll
    for (int i = 0; i < 4; ++i) o[i] = m[i] + log2_hw(s[i]);
    *(f4*)(d2 + (size_t)n * Tt + t4) = o;
}

// ------- merge 4 partials into dP[0] (tier3 path) -------
__global__ __launch_bounds__(256) void ctc_denom_merge4(float* __restrict__ dP)
{
    const int t4 = (blockIdx.x * 256 + threadIdx.x) * 4;
    const int n = blockIdx.y;
    if (t4 >= Tt) return;
    f4 a = LD4(dP + (size_t)n * Tt + t4);
    f4 b = LD4(dP + ((size_t)Nn + n) * Tt + t4);
    f4 c = LD4(dP + ((size_t)2 * Nn + n) * Tt + t4);
    f4 e = LD4(dP + ((size_t)3 * Nn + n) * Tt + t4);
    f4 d;
    #pragma unroll
    for (int i = 0; i < 4; ++i) {
        const float mm = fmaxf(fmaxf(a[i], b[i]), fmaxf(c[i], e[i]));
        d[i] = mm + log2_hw(exp2_hw(a[i] - mm) + exp2_hw(b[i] - mm) +
                            exp2_hw(c[i] - mm) + exp2_hw(e[i] - mm));
    }
    *(f4*)(dP + (size_t)n * Tt + t4) = d;
}

// ------- Kernel 1b: membership-filtered probabilities (+ optional 4-way merge) -------
template<bool MERGE4>
__global__ __launch_bounds__(256) void ctc_prob_sel(
    const float* __restrict__ logits, const float* __restrict__ dP,
    const int* __restrict__ targets, const int* __restrict__ tlen,
    float* __restrict__ P)
{
    const int n = blockIdx.y;
    const int c0 = blockIdx.z * 8;
    __shared__ int needs;
    if (threadIdx.x == 0) needs = (c0 == 0) ? 1 : 0;   // blank always needed
    __syncthreads();
    const int tl = tlen[n];
    if ((int)threadIdx.x < min(tl, Ss)) {
        const int rel = targets[n * Ss + threadIdx.x] - c0;
        if (rel >= 0 && rel < 8) atomicOr(&needs, 1 << rel);
    }
    __syncthreads();
    const int nd = needs;
    if (nd == 0) return;
    const int t4 = (blockIdx.x * 256 + threadIdx.x) * 4;
    if (t4 >= Tt) return;
    f4 d;
    if constexpr (MERGE4) {
        f4 a = LD4(dP + (size_t)n * Tt + t4);
        f4 b = LD4(dP + ((size_t)Nn + n) * Tt + t4);
        f4 c = LD4(dP + ((size_t)2 * Nn + n) * Tt + t4);
        f4 e = LD4(dP + ((size_t)3 * Nn + n) * Tt + t4);
        #pragma unroll
        for (int i = 0; i < 4; ++i) {
            const float mm = fmaxf(fmaxf(a[i], b[i]), fmaxf(c[i], e[i]));
            d[i] = mm + log2_hw(exp2_hw(a[i] - mm) + exp2_hw(b[i] - mm) +
                                exp2_hw(c[i] - mm) + exp2_hw(e[i] - mm));
        }
    } else {
        d = LD4(dP + (size_t)n * Tt + t4);
    }
    const float* __restrict__ src = logits + ((size_t)(n * Cc + c0)) * Tt + t4;
    float* __restrict__ dst = P + ((size_t)(n * Cc + c0)) * Tt + t4;
    #pragma unroll
    for (int c = 0; c < 8; ++c) {
        if ((nd >> c) & 1) {
            f4 v = LD4(src + (size_t)c * Tt);
            f4 o;
            #pragma unroll
            for (int i = 0; i < 4; ++i) o[i] = exp2_hw(fmaf(v[i], IL2f, -d[i]));
            *(f4*)(dst + (size_t)c * Tt) = o;
        }
    }
}

// ---------------- Kernel 2: fwd/bwd recurrence ----------------
// R12 staging (32-step groups, 2-slot LDS ring, counted vmcnt). R16:
// (1) fwd full body runs PERMANENTLY in the swapped layout Q0'=(a2,a0),
//     Q1'=(a3,a1): the step's natural output order — zero shuffles (R12's
//     body paid 4 shufflevectors/step on layout restoration).
// (2) asymmetric mid-split (fwd 11/20 of T, bwd 9/20) balances the ~9-instr
//     fwd body against the ~11-instr bwd body (wall = max of the two).
template<bool PRE>
__global__ __launch_bounds__(64) void ctc_fb_kernel(
    const float* __restrict__ PR, const int* __restrict__ targets,
    const int* __restrict__ tlen, const int* __restrict__ ilen,
    const float* __restrict__ d2, float* __restrict__ wsA, float* __restrict__ wsB)
{
    constexpr int NA = PRE ? 3 : 4;
    constexpr int NLD = NA * 8;
    __shared__ float lds[2][NA][8][64][4];

    const int bid = blockIdx.x;
    const int n = bid >> 1;
    const bool bwd = bid & 1;
    const int lane = threadIdx.x;
    const int tl = tlen[n];
    const int Tn = ilen[n];
    const int L = 2 * tl + 1;
    const int mid = (int)(((long long)Tn * 11) / 20);   // asymmetric split
    const int s0 = 4 * lane;

    const int j1 = min(2 * lane, Ss - 1);
    const int j3 = min(2 * lane + 1, Ss - 1);
    const int base = n * Ss;
    const int tg1 = targets[base + j1];
    const int tg3 = targets[base + j3];
    const int tg1m = targets[base + max(2 * lane - 1, 0)];
    const int tg3p = targets[base + min(2 * lane + 2, Ss - 1)];

    const float sk1f = ((s0 + 1 >= 3) && (tg1 != tg1m)) ? 1.f : 0.f;
    const float sk3f = (tg3 != tg1) ? 1.f : 0.f;
    const float sk1b = ((s0 + 3 < L) && (tg3 != tg1)) ? 1.f : 0.f;
    const float sk3b = ((s0 + 5 < L) && (tg3p != tg3)) ? 1.f : 0.f;

    const float* __restrict__ rB = PR + (size_t)(n * Cc) * Tt;
    const float* __restrict__ r1 = PR + (size_t)(n * Cc + tg1) * Tt;
    const float* __restrict__ r3 = PR + (size_t)(n * Cc + tg3) * Tt;
    const float* __restrict__ rD = d2 + (size_t)n * Tt;

    float a0, a1, a2, a3;
    int E = 0;

    if (!bwd) {
        float pB0, p10;
        if constexpr (PRE) { pB0 = rB[0]; p10 = r1[0]; }
        else {
            const float dv = rD[0];
            pB0 = exp2_hw(fmaf(rB[0], IL2f, -dv));
            p10 = exp2_hw(fmaf(r1[0], IL2f, -dv));
        }
        a0 = (lane == 0) ? pB0 : 0.f;
        a1 = (lane == 0) ? p10 : 0.f;
        a2 = 0.f; a3 = 0.f;
    } else {
        const int te = Tn - 1;
        float pBe, p1e, p3e;
        if constexpr (PRE) { pBe = rB[te]; p1e = r1[te]; p3e = r3[te]; }
        else {
            const float dv = rD[te];
            pBe = exp2_hw(fmaf(rB[te], IL2f, -dv));
            p1e = exp2_hw(fmaf(r1[te], IL2f, -dv));
            p3e = exp2_hw(fmaf(r3[te], IL2f, -dv));
        }
        const int sl = 2 * tl;
        a0 = (s0 == sl) ? pBe : 0.f;
        a1 = (s0 + 1 == sl - 1) ? p1e : 0.f;
        a2 = (s0 + 2 == sl) ? pBe : 0.f;
        a3 = (s0 + 3 == sl - 1) ? p3e : 0.f;
    }

    #define ISSUE(gg, sl) {                                                         \
        const int bo_ = (gg) * 32;                                                  \
        _Pragma("unroll")                                                           \
        for (int j = 0; j < 8; ++j) {                                               \
            gload16(rB + bo_ + 4 * j, &lds[sl][0][j][0][0]);                        \
            gload16(r1 + bo_ + 4 * j, &lds[sl][1][j][0][0]);                        \
            gload16(r3 + bo_ + 4 * j, &lds[sl][2][j][0][0]);                        \
            if constexpr (!PRE) gload16(rD + bo_ + 4 * j, &lds[sl][NA - 1][j][0][0]); \
        }                                                                           \
    }
    #define WAITG() asm volatile("s_waitcnt vmcnt(%0)" :: "n"(NLD) : "memory")
    #define LOADREGS(slc)                                                           \
        f4 vB[8], vU[8], vW[8], vD[8];                                              \
        _Pragma("unroll")                                                           \
        for (int j = 0; j < 8; ++j) {                                               \
            vB[j] = LD4(&lds[slc][0][j][lane][0]);                                  \
            vU[j] = LD4(&lds[slc][1][j][lane][0]);                                  \
            vW[j] = LD4(&lds[slc][2][j][lane][0]);                                  \
            if constexpr (!PRE) vD[j] = LD4(&lds[slc][NA - 1][j][lane][0]);         \
        }                                                                           \
        (void)vD;

    #define RENORM_S(nb) {                                                          \
        const float mx = fmaxf(fmaxf(a0, a1), fmaxf(a2, a3));                       \
        const int me = (int)(__float_as_uint(mx) >> 23);                            \
        const float s2 = __int_as_float((unsigned)(254 - me) << 23);                \
        a0 *= s2; a1 *= s2; a2 *= s2; a3 *= s2;                                     \
        E = (mx > 0.f) ? (E + me - 127) : (nb);                                     \
    }

    if (!bwd) {
        const int tB = mid;
        const int gHi = tB >> 5;

        // Guarded scalar body (boundary groups / !PRE).
        #define BODY_F_G(gg) {                                                      \
            _Pragma("unroll")                                                       \
            for (int w = 0; w < 4; ++w) {                                           \
                const int Eu = wave_shr1_i(E);                                      \
                const int eb = min(max(127 + (Eu - E), 0), 230);                    \
                const float sc = __int_as_float((unsigned)eb << 23);                \
                const float sk1fs = sk1f * sc;                                      \
                _Pragma("unroll")                                                   \
                for (int kk = 0; kk < 8; ++kk) {                                    \
                    const int k = w * 8 + kk;                                       \
                    const int t = (gg) * 32 + k;                                    \
                    if (t >= 1 && t <= tB) {                                        \
                        float pB, p1, p3;                                           \
                        if constexpr (PRE) {                                        \
                            pB = vB[k >> 2][k & 3]; p1 = vU[k >> 2][k & 3];         \
                            p3 = vW[k >> 2][k & 3];                                 \
                        } else {                                                    \
                            const float dv = vD[k >> 2][k & 3];                     \
                            pB = exp2_hw(fmaf(vB[k >> 2][k & 3], IL2f, -dv));       \
                            p1 = exp2_hw(fmaf(vU[k >> 2][k & 3], IL2f, -dv));       \
                            p3 = exp2_hw(fmaf(vW[k >> 2][k & 3], IL2f, -dv));       \
                        }                                                           \
                        const float u3 = wave_shr1(a3);                             \
                        const float n3 = fmaf(a1, sk3f, a3 + a2) * p3;              \
                        const float n2 = (a2 + a1) * pB;                            \
                        const float n1 = fmaf(u3, sk1fs, a1 + a0) * p1;             \
                        const float n0 = fmaf(u3, sc, a0) * pB;                     \
                        a0 = n0; a1 = n1; a2 = n2; a3 = n3;                         \
                    }                                                               \
                }                                                                   \
                RENORM_S(Eu);                                                       \
            }                                                                       \
        }

        // Branch-free packed body, swapped steady-state layout Q0'=(a2,a0),
        // Q1'=(a3,a1): zero shuffles (outputs land already-swapped).
        #define BODY_F_F() {                                                        \
            f2 Q0 = {a2, a0}, Q1 = {a3, a1};                                        \
            _Pragma("unroll")                                                       \
            for (int w = 0; w < 4; ++w) {                                           \
                const int Eu = wave_shr1_i(E);                                      \
                const int eb = min(max(127 + (Eu - E), 0), 230);                    \
                const float sc = __int_as_float((unsigned)eb << 23);                \
                const f2 Ksk = {sk3f, sk1f * sc};                                   \
                const f2 K1s = {1.0f, sc};                                          \
                _Pragma("unroll")                                                   \
                for (int kk = 0; kk < 8; ++kk) {                                    \
                    const int k = w * 8 + kk;                                       \
                    const float pB = vB[k >> 2][k & 3];                             \
                    const f2 P31 = {vW[k >> 2][k & 3], vU[k >> 2][k & 3]};          \
                    const f2 PBB = {pB, pB};                                        \
                    const float u3 = wave_shr1(Q1.x);      /* a3 from lane-1 */     \
                    const f2 M = {Q1.y, u3};               /* (a1, u3) */           \
                    const f2 S = Q1 + Q0;                  /* (a3+a2, a1+a0) */     \
                    const f2 F = __builtin_elementwise_fma(M, Ksk, S);              \
                    const f2 G = __builtin_elementwise_fma(M, K1s, Q0);             \
                    Q1 = F * P31;                          /* (n3, n1) */           \
                    Q0 = G * PBB;                          /* (n2, n0) */           \
                }                                                                   \
                const f2 mxv = __builtin_elementwise_max(Q0, Q1);                   \
                const float mx = fmaxf(mxv.x, mxv.y);                               \
                const int me = (int)(__float_as_uint(mx) >> 23);                    \
                const float s2 = __int_as_float((unsigned)(254 - me) << 23);        \
                const f2 S2 = {s2, s2};                                             \
                Q0 *= S2; Q1 *= S2;                                                 \
                E = (mx > 0.f) ? (E + me - 127) : Eu;                               \
            }                                                                       \
            a2 = Q0.x; a0 = Q0.y; a3 = Q1.x; a1 = Q1.y;                             \
        }

        ISSUE(0, 0);
        int cur = 0;
        for (int g = 0; g <= gHi; ++g) {
            ISSUE(min(g + 1, gHi), cur ^ 1);
            WAITG();
            LOADREGS(cur);
            cur ^= 1;
            if (PRE && g >= 1 && g * 32 + 31 <= tB) { BODY_F_F(); }
            else                                    { BODY_F_G(g); }
        }
        #undef BODY_F_G
        #undef BODY_F_F
    } else {
        const int tB = Tn - 2, tA = mid + 1;
        const int gHi = tB >> 5, gLo = tA >> 5;

        #define BODY_B_G(gg) {                                                      \
            _Pragma("unroll")                                                       \
            for (int w = 3; w >= 0; --w) {                                          \
                const int Ed = wave_shl1_i(E);                                      \
                const int eb = min(max(127 + (Ed - E), 0), 230);                    \
                const float sc = __int_as_float((unsigned)eb << 23);                \
                const float sk3bs = sk3b * sc;                                      \
                _Pragma("unroll")                                                   \
                for (int kk = 7; kk >= 0; --kk) {                                   \
                    const int k = w * 8 + kk;                                       \
                    const int t = (gg) * 32 + k;                                    \
                    if (t >= tA && t <= tB) {                                       \
                        float pB, p1, p3;                                           \
                        if constexpr (PRE) {                                        \
                            pB = vB[k >> 2][k & 3]; p1 = vU[k >> 2][k & 3];         \
                            p3 = vW[k >> 2][k & 3];                                 \
                        } else {                                                    \
                            const float dv = vD[k >> 2][k & 3];                     \
                            pB = exp2_hw(fmaf(vB[k >> 2][k & 3], IL2f, -dv));       \
                            p1 = exp2_hw(fmaf(vU[k >> 2][k & 3], IL2f, -dv));       \
                            p3 = exp2_hw(fmaf(vW[k >> 2][k & 3], IL2f, -dv));       \
                        }                                                           \
                        const float d0 = wave_shl1(a0);                             \
                        const float d1 = wave_shl1(a1);                             \
                        const float n0 = (a0 + a1) * pB;                            \
                        const float n1 = fmaf(a3, sk1b, a1 + a2) * p1;              \
                        const float n2 = (a2 + a3) * pB;                            \
                        const float n3 = fmaf(d1, sk3bs, fmaf(d0, sc, a3)) * p3;    \
                        a0 = n0; a1 = n1; a2 = n2; a3 = n3;                         \
                    }                                                               \
                }                                                                   \
                RENORM_S(Ed);                                                       \
            }                                                                       \
        }

        #define BODY_B_F() {                                                        \
            f2 Q0 = {a0, a2}, Q1 = {a1, a3};                                        \
            _Pragma("unroll")                                                       \
            for (int w = 3; w >= 0; --w) {                                          \
                const int Ed = wave_shl1_i(E);                                      \
                const int eb = min(max(127 + (Ed - E), 0), 230);                    \
                const float sc = __int_as_float((unsigned)eb << 23);                \
                const f2 K1s = {1.0f, sc};                                          \
                const f2 Ksk = {sk1b, sk3b * sc};                                   \
                _Pragma("unroll")                                                   \
                for (int kk = 7; kk >= 0; --kk) {                                   \
                    const int k = w * 8 + kk;                                       \
                    const float pB = vB[k >> 2][k & 3];                             \
                    const f2 P13 = {vU[k >> 2][k & 3], vW[k >> 2][k & 3]};          \
                    const f2 PBB = {pB, pB};                                        \
                    const float d0 = wave_shl1(Q0.x);                               \
                    const float d1 = wave_shl1(Q1.x);                               \
                    const f2 S = Q0 + Q1;                                           \
                    const f2 A2 = __builtin_elementwise_fma((f2){Q0.y, d0}, K1s, Q1); \
                    const f2 B2 = __builtin_elementwise_fma((f2){Q1.y, d1}, Ksk, A2); \
                    Q1 = B2 * P13;                                                  \
                    Q0 = S * PBB;                                                   \
                }                                                                   \
                const f2 mxv = __builtin_elementwise_max(Q0, Q1);                   \
                const float mx = fmaxf(mxv.x, mxv.y);                               \
                const int me = (int)(__float_as_uint(mx) >> 23);                    \
                const float s2 = __int_as_float((unsigned)(254 - me) << 23);        \
                const f2 S2 = {s2, s2};                                             \
                Q0 *= S2; Q1 *= S2;                                                 \
                E = (mx > 0.f) ? (E + me - 127) : Ed;                               \
            }                                                                       \
            a0 = Q0.x; a2 = Q0.y; a1 = Q1.x; a3 = Q1.y;                             \
        }

        ISSUE(gHi, 0);
        int cur = 0;
        for (int g = gHi; g >= gLo; --g) {
            ISSUE(max(g - 1, 0), cur ^ 1);
            WAITG();
            LOADREGS(cur);
            cur ^= 1;
            if (PRE && g * 32 >= tA && g * 32 + 31 <= tB) { BODY_B_F(); }
            else                                          { BODY_B_G(g); }
        }
        #undef BODY_B_G
        #undef BODY_B_F
    }
    #undef ISSUE
    #undef WAITG
    #undef LOADREGS
    #undef RENORM_S

    float* dst = (bwd ? wsB : wsA) + n * 256;
    const float Ef = (float)E;
    f4 o;
    o[0] = (s0     < L && a0 > 0.f) ? log2_hw(a0) + Ef : NEGV;
    o[1] = (s0 + 1 < L && a1 > 0.f) ? log2_hw(a1) + Ef : NEGV;
    o[2] = (s0 + 2 < L && a2 > 0.f) ? log2_hw(a2) + Ef : NEGV;
    o[3] = (s0 + 3 < L && a3 > 0.f) ? log2_hw(a3) + Ef : NEGV;
    *(f4*)(dst + s0) = o;
}

// ---------------- Kernel 3: splice alpha*beta, lse over states, mean ----------------
__global__ __launch_bounds__(64) void ctc_combine_kernel(
    const float* __restrict__ wsA, const float* __restrict__ wsB,
    const int* __restrict__ targets, const int* __restrict__ tlen,
    float* __restrict__ out)
{
    const int n = blockIdx.x;
    const int lane = threadIdx.x;
    const int tl = tlen[n];
    const int L = 2 * tl + 1;
    float vals[4];
    float vmax = NEGV;
    #pragma unroll
    for (int k = 0; k < 4; ++k) {
        const int s = lane + (k << 6);
        float v = NEGV;
        if (s < L) {
            const float al = wsA[n * 256 + s];
            const float b0 = wsB[n * 256 + s];
            const float b1 = (s + 1 < L) ? wsB[n * 256 + s + 1] : NEGV;
            const bool skip = (s & 1) && (s + 2 < L) &&
                (targets[n * Ss + (s >> 1) + 1] != targets[n * Ss + (s >> 1)]);
            const float b2 = skip ? wsB[n * 256 + s + 2] : NEGV;
            const float m3 = fmaxf(fmaxf(b0, b1), b2);
            const float B = m3 + log2_hw(exp2_hw(b0 - m3) + exp2_hw(b1 - m3) + exp2_hw(b2 - m3));
            v = al + B;
        }
        vals[k] = v;
        vmax = fmaxf(vmax, v);
    }
    #pragma unroll
    for (int o = 32; o; o >>= 1) vmax = fmaxf(vmax, __shfl_xor(vmax, o));
    float ssum = 0.f;
    #pragma unroll
    for (int k = 0; k < 4; ++k) ssum += exp2_hw(vals[k] - vmax);
    #pragma unroll
    for (int o = 32; o; o >>= 1) ssum += __shfl_xor(ssum, o);
    if (lane == 0) {
        const float total2 = vmax + log2_hw(ssum);
        const float loss = -LN2f * total2;
        atomicAdd(out, loss / ((float)tl * (float)Nn));
    }
}

extern "C" void kernel_launch(void* const* d_in, const int* in_sizes, int n_in,
                              void* d_out, int out_size, void* d_ws, size_t ws_size,
                              hipStream_t stream) {
    const float* logits = (const float*)d_in[0];
    const int* targets  = (const int*)d_in[1];
    const int* tlen     = (const int*)d_in[2];
    const int* ilen     = (const int*)d_in[3];
    float* out = (float*)d_out;

    float* wsA = (float*)d_ws;                         // Nn*256
    float* wsB = wsA + Nn * 256;                       // Nn*256
    float* dP  = wsB + Nn * 256;                       // up to 4 * Nn*Tt partials
    float* P1  = dP + (size_t)4 * Nn * Tt;             // tier1 P
    float* P2  = dP + (size_t)Nn * Tt;                 // tier2 P

    const size_t base = (size_t)Nn * 512;
    const size_t need1 = (base + (size_t)4 * Nn * Tt + (size_t)Nn * Cc * Tt) * 4;
    const size_t need2 = (base + (size_t)Nn * Tt + (size_t)Nn * Cc * Tt) * 4;

    hipMemsetAsync(d_out, 0, sizeof(float), stream);
    if (ws_size >= need1) {
        ctc_denom_part4<<<dim3(4, Nn, 4), 256, 0, stream>>>(logits, dP);
        ctc_prob_sel<true><<<dim3(4, Nn, 8), 256, 0, stream>>>(logits, dP, targets, tlen, P1);
        ctc_fb_kernel<true><<<Nn * 2, 64, 0, stream>>>(P1, targets, tlen, ilen, dP, wsA, wsB);
    } else if (ws_size >= need2) {
        ctc_denom_kernel<<<dim3(4, Nn), 256, 0, stream>>>(logits, dP);
        ctc_prob_sel<false><<<dim3(4, Nn, 8), 256, 0, stream>>>(logits, dP, targets, tlen, P2);
        ctc_fb_kernel<true><<<Nn * 2, 64, 0, stream>>>(P2, targets, tlen, ilen, dP, wsA, wsB);
    } else {
        ctc_denom_part4<<<dim3(4, Nn, 4), 256, 0, stream>>>(logits, dP);
        ctc_denom_merge4<<<dim3(4, Nn), 256, 0, stream>>>(dP);
        ctc_fb_kernel<false><<<Nn * 2, 64, 0, stream>>>(logits, targets, tlen, ilen, dP, wsA, wsB);
    }
    ctc_combine_kernel<<<Nn, 64, 0, stream>>>(wsA, wsB, targets, tlen, out);
}